// Round 13
// baseline (169.417 us; speedup 1.0000x reference)
//
#include <hip/hip_runtime.h>
#include <hip/hip_fp8.h>

#define NN 50000
#define NE 800000
#define PREP_BLOCKS 784
#define PREP_THREADS (PREP_BLOCKS * 256)

typedef __bf16 bf16x8 __attribute__((ext_vector_type(8)));
typedef float  f32x4  __attribute__((ext_vector_type(4)));
typedef float  f32x2  __attribute__((ext_vector_type(2)));

#if defined(__has_builtin)
#if __has_builtin(__builtin_amdgcn_cvt_pk_f32_fp8)
#define HAVE_CVT_PK_FP8 1
#endif
#endif

__device__ __forceinline__ float frelu(float x) { return fmaxf(x, 0.f); }

__device__ __forceinline__ float fp8_to_f32(unsigned char b) {
    __hip_fp8_e4m3 t; t.__x = (__hip_fp8_storage_t)b; return (float)t;
}
__device__ __forceinline__ unsigned char f32_to_fp8(float f) {
    return (unsigned char)__hip_fp8_e4m3(f).__x;
}

// ===========================================================================
// prep: weight prep for later kernels + agg_edge zero + histogram with ranks
//       + Pa(fp8)/Pb(bf16) precompute (We1 via block-local LDS transpose).
__global__ __launch_bounds__(256) void prep_kernel(
    const float* __restrict__ nf, const int* __restrict__ el,
    const float* __restrict__ We1, const float* __restrict__ We2,
    const float* __restrict__ Wc1, const float* __restrict__ Wn1,
    const float* __restrict__ Wn2, const float* __restrict__ be1,
    __bf16* __restrict__ W2T,  __bf16* __restrict__ Wc1T,
    __bf16* __restrict__ Wn1T, __bf16* __restrict__ Wn2T,
    unsigned char* __restrict__ Pa, __bf16* __restrict__ Pb,
    int* __restrict__ deg, int* __restrict__ rank, float* __restrict__ agg_edge)
{
    __shared__ __align__(16) __bf16 w1lds[64 * 128];
    if (blockIdx.x < 196) {
        for (int idx = threadIdx.x; idx < 64 * 128; idx += 256) {
            const int k = idx >> 6;          // 0..127
            const int j = idx & 63;
            w1lds[j * 128 + (k ^ ((j & 7) << 3))] = (__bf16)We1[k * 64 + j];
        }
    }

    const int tid = blockIdx.x * 256 + threadIdx.x;

    // ---- weight transpose for later kernels (first 4096 threads) ----
    if (tid < 4096) {
        const int j = tid & 63, k = tid >> 6;
        W2T [j * 64 + k] = (__bf16)We2[k * 64 + j];
        Wc1T[j * 64 + k] = (__bf16)Wc1[k * 64 + j];
        Wn2T[j * 64 + k] = (__bf16)Wn2[k * 64 + j];
        Wn1T[j * 128 + k]      = (__bf16)Wn1[k * 64 + j];
        Wn1T[j * 128 + 64 + k] = (__bf16)Wn1[(64 + k) * 64 + j];
    }

    // ---- agg_edge zero (3.2M floats as float4) ----
    {
        const f32x4 z = (f32x4){0.f, 0.f, 0.f, 0.f};
        for (int i = tid; i < NN * 16; i += PREP_THREADS)
            ((f32x4*)agg_edge)[i] = z;
    }

    // ---- histogram + rank (deg memset to 0 before this kernel) ----
    for (int e = tid; e < NE; e += PREP_THREADS) {
        const int2 pr = ((const int2*)el)[e];
        rank[e] = atomicAdd(&deg[pr.y], 1);
    }

    if (blockIdx.x >= 196) return;
    __syncthreads();   // w1lds ready

    // ---- Pa/Pb MFMA precompute ----
    const int w = threadIdx.x >> 6, lane = threadIdx.x & 63;
    const int c = lane & 15, g = lane >> 4;
    const int mbase = blockIdx.x * 256 + w * 64;

    bf16x8 af[4][2];
#pragma unroll
    for (int m = 0; m < 4; ++m) {
        int node = mbase + m * 16 + c;
        node = (node < NN) ? node : (NN - 1);
#pragma unroll
        for (int s = 0; s < 2; ++s) {
            const int k0 = s * 32 + g * 8;
            const float4 v0 = *(const float4*)(nf + (size_t)node * 64 + k0);
            const float4 v1 = *(const float4*)(nf + (size_t)node * 64 + k0 + 4);
            bf16x8 a;
            a[0] = (__bf16)v0.x; a[1] = (__bf16)v0.y; a[2] = (__bf16)v0.z; a[3] = (__bf16)v0.w;
            a[4] = (__bf16)v1.x; a[5] = (__bf16)v1.y; a[6] = (__bf16)v1.z; a[7] = (__bf16)v1.w;
            af[m][s] = a;
        }
    }

    // Pa = nf @ We1[0:64,:]  -> fp8 e4m3
    {
        f32x4 cc[4][4];
#pragma unroll
        for (int m = 0; m < 4; ++m)
#pragma unroll
            for (int n = 0; n < 4; ++n) cc[m][n] = (f32x4){0.f, 0.f, 0.f, 0.f};
#pragma unroll
        for (int n = 0; n < 4; ++n)
#pragma unroll
            for (int s = 0; s < 2; ++s) {
                const int j = n * 16 + c;
                const bf16x8 b = *(const bf16x8*)&w1lds[j * 128 + ((s * 32 + g * 8) ^ ((j & 7) << 3))];
#pragma unroll
                for (int m = 0; m < 4; ++m)
                    cc[m][n] = __builtin_amdgcn_mfma_f32_16x16x32_bf16(af[m][s], b, cc[m][n], 0, 0, 0);
            }
#pragma unroll
        for (int m = 0; m < 4; ++m)
#pragma unroll
            for (int n = 0; n < 4; ++n)
#pragma unroll
                for (int r = 0; r < 4; ++r) {
                    const int node = mbase + m * 16 + g * 4 + r;
                    if (node < NN) Pa[(size_t)node * 64 + n * 16 + c] = f32_to_fp8(cc[m][n][r]);
                }
    }
    // Pb = nf @ We1[64:128,:] + be1 (folded)
    {
        f32x4 cc[4][4];
#pragma unroll
        for (int m = 0; m < 4; ++m)
#pragma unroll
            for (int n = 0; n < 4; ++n) cc[m][n] = (f32x4){0.f, 0.f, 0.f, 0.f};
#pragma unroll
        for (int n = 0; n < 4; ++n)
#pragma unroll
            for (int s = 0; s < 2; ++s) {
                const int j = n * 16 + c;
                const bf16x8 b = *(const bf16x8*)&w1lds[j * 128 + 64 + ((s * 32 + g * 8) ^ ((j & 7) << 3))];
#pragma unroll
                for (int m = 0; m < 4; ++m)
                    cc[m][n] = __builtin_amdgcn_mfma_f32_16x16x32_bf16(af[m][s], b, cc[m][n], 0, 0, 0);
            }
#pragma unroll
        for (int n = 0; n < 4; ++n) {
            const float bb = be1[n * 16 + c];
#pragma unroll
            for (int m = 0; m < 4; ++m)
#pragma unroll
                for (int r = 0; r < 4; ++r) {
                    const int node = mbase + m * 16 + g * 4 + r;
                    if (node < NN) Pb[(size_t)node * 64 + n * 16 + c] = (__bf16)(cc[m][n][r] + bb);
                }
        }
    }
}

// ===========================================================================
// alloc1: per-256-node chunk: exclusive prefix of deg within chunk + chunk sum.
__global__ __launch_bounds__(256) void alloc1_kernel(
    const int* __restrict__ deg, int* __restrict__ base_rel,
    int* __restrict__ chunkSum)
{
    __shared__ int wsum[4];
    const int t = threadIdx.x;
    const int n = blockIdx.x * 256 + t;
    const int lid = t & 63, wid = t >> 6;
    const int d = (n < NN) ? deg[n] : 0;
    int pre = d;
#pragma unroll
    for (int off = 1; off < 64; off <<= 1) {
        const int v = __shfl_up(pre, off);
        if (lid >= off) pre += v;
    }
    if (lid == 63) wsum[wid] = pre;
    __syncthreads();
    int woff = 0;
#pragma unroll
    for (int i = 0; i < 4; ++i) if (i < wid) woff += wsum[i];
    if (n < NN) base_rel[n] = woff + pre - d;
    if (t == 255) chunkSum[blockIdx.x] = woff + pre;
}

// ===========================================================================
// scatter: block-local scan of the 196 chunk sums (alloc2 fused) +
//          atomic-free placement + agg3 zeroing.
__global__ __launch_bounds__(256) void scatter_kernel(
    const int* __restrict__ el, const int* __restrict__ base_rel,
    const int* __restrict__ chunkSum, const int* __restrict__ rank,
    int2* __restrict__ sorted_el, float* __restrict__ agg3)
{
    __shared__ int s[256];
    __shared__ int cOff[196];
    const int t = threadIdx.x;
    const int v0 = (t < 196) ? chunkSum[t] : 0;
    s[t] = v0;
    __syncthreads();
    for (int d = 1; d < 256; d <<= 1) {
        const int v = (t >= d) ? s[t - d] : 0;
        __syncthreads();
        s[t] += v;
        __syncthreads();
    }
    if (t < 196) cOff[t] = s[t] - v0;
    __syncthreads();

    const int e = blockIdx.x * 256 + t;
    if (e < NN * 3) agg3[e] = 0.f;
    const int2 pr = ((const int2*)el)[e];
    sorted_el[cOff[pr.y >> 8] + base_rel[pr.y] + rank[e]] = pr;
}

// ===========================================================================
// Edge kernel. 2 waves/block, 64 edges/wave. Pa fp8 (L2-resident), Pb bf16.
// ALL 16 Pa/Pb gathers hoisted into explicit register arrays and issued
// back-to-back BEFORE any A-build VALU -> one latency exposure, not ~4.
// launch_bounds(128,3): VGPR cap ~170 so the ~115-reg peak cannot spill.
__global__ __launch_bounds__(128, 3) void edge_mfma(
    const unsigned char* __restrict__ Pa, const __bf16* __restrict__ Pb,
    const float* __restrict__ coord, const int2* __restrict__ sorted_el,
    const float* __restrict__ We1,
    const __bf16* __restrict__ W2T, const float* __restrict__ be2,
    const __bf16* __restrict__ Wc1T, const float* __restrict__ bc1,
    const float* __restrict__ wc,
    float* __restrict__ agg_edge, float* __restrict__ agg3)
{
    __shared__ __align__(16) __bf16 tile[2][64 * 32];  // half-width ef, swizzled
    __shared__ int   nout_s[2][64];
    __shared__ float tw_s[2][64];

    const int w    = threadIdx.x >> 6;                 // 0..1
    const int lane = threadIdx.x & 63;
    const int c    = lane & 15;
    const int g    = lane >> 4;
    const int ebase = blockIdx.x * 128 + w * 64;       // NE = 6250*128 exact

    // ---- phase 1: lane = edge (grouped+ascending by nout) ----
    const int2 pr = sorted_el[ebase + lane];
    const int nin = pr.x, nout = pr.y;
    nout_s[w][lane] = nout;
    const float cdx = coord[3 * nout + 0] - coord[3 * nin + 0];
    const float cdy = coord[3 * nout + 1] - coord[3 * nin + 1];
    const float cdz = coord[3 * nout + 2] - coord[3 * nin + 2];
    const float radial = cdx * cdx + cdy * cdy + cdz * cdz;

    // ---- hoist: issue ALL Pa/Pb gathers before any A-build arithmetic ----
    uint2  pu[4][2];     // 16 VGPR raw fp8
    bf16x8 pbv[4][2];    // 32 VGPR raw bf16
    float  rads[4];
#pragma unroll
    for (int m = 0; m < 4; ++m) {
        const int e  = m * 16 + c;
        const int ni = __shfl(nin, e);
        const int no = __shfl(nout, e);
        rads[m] = __shfl(radial, e);
        const unsigned char* paRow = Pa + (size_t)ni * 64;
        const __bf16* pbRow = Pb + (size_t)no * 64;
#pragma unroll
        for (int s = 0; s < 2; ++s) {
            const int k0 = s * 32 + g * 8;
            pu[m][s]  = *(const uint2*)(paRow + k0);
            pbv[m][s] = *(const bf16x8*)(pbRow + k0);
        }
    }

    // We1 radial row (be1 folded into Pb at prep)
    float wv[2][8];
#pragma unroll
    for (int s = 0; s < 2; ++s) {
        const int k0 = s * 32 + g * 8;
        const float4 a = *(const float4*)(We1 + 128 * 64 + k0);
        const float4 b = *(const float4*)(We1 + 128 * 64 + k0 + 4);
        wv[s][0] = a.x; wv[s][1] = a.y; wv[s][2] = a.z; wv[s][3] = a.w;
        wv[s][4] = b.x; wv[s][5] = b.y; wv[s][6] = b.z; wv[s][7] = b.w;
    }

    // ---- A-build: pure VALU pass over the hoisted registers ----
    bf16x8 af[4][2];
#pragma unroll
    for (int m = 0; m < 4; ++m) {
        const float rad = rads[m];
#pragma unroll
        for (int s = 0; s < 2; ++s) {
            const uint2 puv = pu[m][s];
            const bf16x8 pb = pbv[m][s];
            float pav[8];
#if defined(HAVE_CVT_PK_FP8)
            {
                const f32x2 v01 = __builtin_amdgcn_cvt_pk_f32_fp8((int)puv.x, false);
                const f32x2 v23 = __builtin_amdgcn_cvt_pk_f32_fp8((int)puv.x, true);
                const f32x2 v45 = __builtin_amdgcn_cvt_pk_f32_fp8((int)puv.y, false);
                const f32x2 v67 = __builtin_amdgcn_cvt_pk_f32_fp8((int)puv.y, true);
                pav[0] = v01[0]; pav[1] = v01[1]; pav[2] = v23[0]; pav[3] = v23[1];
                pav[4] = v45[0]; pav[5] = v45[1]; pav[6] = v67[0]; pav[7] = v67[1];
            }
#else
#pragma unroll
            for (int i = 0; i < 8; ++i) {
                const unsigned char pbyte =
                    (unsigned char)(((i < 4 ? puv.x : puv.y) >> (8 * (i & 3))) & 0xFF);
                pav[i] = fp8_to_f32(pbyte);
            }
#endif
            bf16x8 a;
#pragma unroll
            for (int i = 0; i < 8; ++i)
                a[i] = (__bf16)frelu(pav[i] + (float)pb[i] + rad * wv[s][i]);
            af[m][s] = a;
        }
    }

    // ---- GEMM1 + ef staging + agg, in two 32-column phases ----
    bf16x8 a2[4][2];
#pragma unroll
    for (int p = 0; p < 2; ++p) {
        f32x4 c1h[4][2];
#pragma unroll
        for (int q = 0; q < 2; ++q) {
            const float b = be2[(2 * p + q) * 16 + c];
#pragma unroll
            for (int m = 0; m < 4; ++m) c1h[m][q] = (f32x4){b, b, b, b};
        }
#pragma unroll
        for (int q = 0; q < 2; ++q)
#pragma unroll
            for (int s = 0; s < 2; ++s) {
                const bf16x8 b = *(const bf16x8*)(W2T + ((2 * p + q) * 16 + c) * 64 + s * 32 + g * 8);
#pragma unroll
                for (int m = 0; m < 4; ++m)
                    c1h[m][q] = __builtin_amdgcn_mfma_f32_16x16x32_bf16(af[m][s], b, c1h[m][q], 0, 0, 0);
            }

#pragma unroll
        for (int m = 0; m < 4; ++m)
#pragma unroll
            for (int q = 0; q < 2; ++q)
#pragma unroll
                for (int r = 0; r < 4; ++r) {
                    const int e = m * 16 + g * 4 + r;
                    const int lc = q * 16 + c;
                    tile[w][e * 32 + (lc ^ (((e >> 1) & 3) << 3))] = (__bf16)frelu(c1h[m][q][r]);
                }

#pragma unroll
        for (int m = 0; m < 4; ++m) {
            const int e = m * 16 + c;
            a2[m][p] = *(const bf16x8*)&tile[w][e * 32 + ((g * 8) ^ (((e >> 1) & 3) << 3))];
        }

        // agg_edge for cols p*32..p*32+31: 2 lanes/col, rows split 0-31/32-63
        {
            const int lc = lane & 31;
            const int rbase = (lane >> 5) * 32;
            int cur = nout_s[w][rbase];
            float acc = 0.f;
#pragma unroll 4
            for (int rr = 0; rr < 32; ++rr) {
                const int r = rbase + rr;
                acc += (float)tile[w][r * 32 + (lc ^ (((r >> 1) & 3) << 3))];
                const int nxt = (rr < 31) ? nout_s[w][r + 1] : -1;
                if (nxt != cur) {
                    atomicAdd(&agg_edge[(size_t)cur * 64 + p * 32 + lc], acc);
                    acc = 0.f;
                    cur = nxt;
                }
            }
        }
    }

    // ---- GEMM2 (t = relu(ef @ Wc1 + bc1)) folded into tw per n ----
    f32x4 twp[4];
#pragma unroll
    for (int m = 0; m < 4; ++m) twp[m] = (f32x4){0.f, 0.f, 0.f, 0.f};
#pragma unroll
    for (int n = 0; n < 4; ++n) {
        const float b = bc1[n * 16 + c];
        const float wn = wc[n * 16 + c];
        f32x4 c2[4];
#pragma unroll
        for (int m = 0; m < 4; ++m) c2[m] = (f32x4){b, b, b, b};
#pragma unroll
        for (int s = 0; s < 2; ++s) {
            const bf16x8 bb = *(const bf16x8*)(Wc1T + (n * 16 + c) * 64 + s * 32 + g * 8);
#pragma unroll
            for (int m = 0; m < 4; ++m)
                c2[m] = __builtin_amdgcn_mfma_f32_16x16x32_bf16(a2[m][s], bb, c2[m], 0, 0, 0);
        }
#pragma unroll
        for (int m = 0; m < 4; ++m)
#pragma unroll
            for (int r = 0; r < 4; ++r)
                twp[m][r] = fmaf(frelu(c2[m][r]), wn, twp[m][r]);
    }

    // ---- tw: 16-lane butterfly reduce ----
#pragma unroll
    for (int m = 0; m < 4; ++m) {
#pragma unroll
        for (int r = 0; r < 4; ++r) {
            float p = twp[m][r];
            p += __shfl_xor(p, 1);
            p += __shfl_xor(p, 2);
            p += __shfl_xor(p, 4);
            p += __shfl_xor(p, 8);
            if (c == 0) tw_s[w][m * 16 + g * 4 + r] = p;
        }
    }

    // ---- coord agg: 48 lanes = 16 row-chunks x 3 dims, run-compressed ----
    {
        const bool act = (lane < 48);
        const int dim = lane % 3;
        const int chunk = act ? (lane / 3) : 0;       // 0..15
        const int r0 = chunk * 4;
        int cur = nout_s[w][r0];
        float acc = 0.f;
#pragma unroll
        for (int rr = 0; rr < 4; ++rr) {
            const int r = r0 + rr;
            const float sx = __shfl(cdx, r);
            const float sy = __shfl(cdy, r);
            const float sz = __shfl(cdz, r);
            const float cdv = (dim == 0) ? sx : (dim == 1) ? sy : sz;
            acc += cdv * tw_s[w][r];
            const int nxt = (rr < 3) ? nout_s[w][r + 1] : -1;
            if (nxt != cur) {
                if (act) atomicAdd(&agg3[3 * cur + dim], acc);
                acc = 0.f;
                cur = nxt;
            }
        }
    }
}

// ===========================================================================
// Node kernel: coord finalize + node MLP via MFMA. 2 waves/block (barrier-free).
__global__ __launch_bounds__(128) void node_mfma(
    const float* __restrict__ nf, const float* __restrict__ coord,
    const float* __restrict__ agg_edge, const int* __restrict__ deg,
    float* agg3_coordout,
    const __bf16* __restrict__ Wn1T, const float* __restrict__ bn1,
    const __bf16* __restrict__ Wn2T, const float* __restrict__ bn2,
    float* __restrict__ out_feat)
{
    __shared__ __align__(16) __bf16 tile[2][64 * 64];
    const int t = threadIdx.x;
    const int w = t >> 6, lane = t & 63, c = lane & 15, g = lane >> 4;
    const int nblk = blockIdx.x * 128;

    const int nodeT = nblk + t;
    if (nodeT < NN) {
        const float invc = 1.f / fmaxf((float)deg[nodeT], 1.f);
#pragma unroll
        for (int d = 0; d < 3; ++d) {
            const float a = agg3_coordout[3 * nodeT + d];
            agg3_coordout[3 * nodeT + d] = coord[3 * nodeT + d] + a * invc;
        }
    }

    const int mbase = nblk + w * 64;

    bf16x8 a1[4][4];
#pragma unroll
    for (int m = 0; m < 4; ++m) {
        int node = mbase + m * 16 + c;
        node = (node < NN) ? node : (NN - 1);
#pragma unroll
        for (int s = 0; s < 4; ++s) {
            const int k0 = s * 32 + g * 8;
            const float* src = (k0 < 64) ? (nf + (size_t)node * 64 + k0)
                                         : (agg_edge + (size_t)node * 64 + (k0 - 64));
            const float4 v0 = *(const float4*)src;
            const float4 v1 = *(const float4*)(src + 4);
            bf16x8 a;
            a[0] = (__bf16)v0.x; a[1] = (__bf16)v0.y; a[2] = (__bf16)v0.z; a[3] = (__bf16)v0.w;
            a[4] = (__bf16)v1.x; a[5] = (__bf16)v1.y; a[6] = (__bf16)v1.z; a[7] = (__bf16)v1.w;
            a1[m][s] = a;
        }
    }

    f32x4 c1[4][4];
#pragma unroll
    for (int n = 0; n < 4; ++n) {
        const float b = bn1[n * 16 + c];
#pragma unroll
        for (int m = 0; m < 4; ++m) c1[m][n] = (f32x4){b, b, b, b};
    }
#pragma unroll
    for (int n = 0; n < 4; ++n)
#pragma unroll
        for (int s = 0; s < 4; ++s) {
            const bf16x8 b = *(const bf16x8*)(Wn1T + (n * 16 + c) * 128 + s * 32 + g * 8);
#pragma unroll
            for (int m = 0; m < 4; ++m)
                c1[m][n] = __builtin_amdgcn_mfma_f32_16x16x32_bf16(a1[m][s], b, c1[m][n], 0, 0, 0);
        }

#pragma unroll
    for (int m = 0; m < 4; ++m)
#pragma unroll
        for (int n = 0; n < 4; ++n)
#pragma unroll
            for (int r = 0; r < 4; ++r) {
                const int e = m * 16 + g * 4 + r;
                tile[w][e * 64 + ((n * 16 + c) ^ ((e & 7) << 3))] = (__bf16)frelu(c1[m][n][r]);
            }

    bf16x8 a2[4][2];
#pragma unroll
    for (int m = 0; m < 4; ++m) {
        const int e = m * 16 + c;
#pragma unroll
        for (int s = 0; s < 2; ++s) {
            const int k0 = s * 32 + g * 8;
            a2[m][s] = *(const bf16x8*)&tile[w][e * 64 + (k0 ^ ((e & 7) << 3))];
        }
    }
    f32x4 c2[4][4];
#pragma unroll
    for (int n = 0; n < 4; ++n) {
        const float b = bn2[n * 16 + c];
#pragma unroll
        for (int m = 0; m < 4; ++m) c2[m][n] = (f32x4){b, b, b, b};
    }
#pragma unroll
    for (int n = 0; n < 4; ++n)
#pragma unroll
        for (int s = 0; s < 2; ++s) {
            const bf16x8 b = *(const bf16x8*)(Wn2T + (n * 16 + c) * 64 + s * 32 + g * 8);
#pragma unroll
            for (int m = 0; m < 4; ++m)
                c2[m][n] = __builtin_amdgcn_mfma_f32_16x16x32_bf16(a2[m][s], b, c2[m][n], 0, 0, 0);
        }

#pragma unroll
    for (int m = 0; m < 4; ++m)
#pragma unroll
        for (int n = 0; n < 4; ++n)
#pragma unroll
            for (int r = 0; r < 4; ++r) {
                const int node = mbase + m * 16 + g * 4 + r;
                if (node < NN) {
                    const int col = n * 16 + c;
                    out_feat[(size_t)node * 64 + col] =
                        nf[(size_t)node * 64 + col] + c2[m][n][r];
                }
            }
}

// ===========================================================================
extern "C" void kernel_launch(void* const* d_in, const int* in_sizes, int n_in,
                              void* d_out, int out_size, void* d_ws, size_t ws_size,
                              hipStream_t stream)
{
    const float* nf    = (const float*)d_in[0];
    const float* coord = (const float*)d_in[1];
    const int*   el    = (const int*)d_in[2];
    const float* We1   = (const float*)d_in[3];
    const float* be1   = (const float*)d_in[4];
    const float* We2   = (const float*)d_in[5];
    const float* be2   = (const float*)d_in[6];
    const float* Wn1   = (const float*)d_in[7];
    const float* bn1   = (const float*)d_in[8];
    const float* Wn2   = (const float*)d_in[9];
    const float* bn2   = (const float*)d_in[10];
    const float* Wc1   = (const float*)d_in[11];
    const float* bc1   = (const float*)d_in[12];
    const float* wc    = (const float*)d_in[13];

    float* out_feat  = (float*)d_out;               // N*64 f32
    float* out_coord = out_feat + (size_t)NN * 64;  // N*3 f32

    unsigned char* Pa = (unsigned char*)d_out;       // 3.2MB of out_feat region
    int*    rank = (int*)((char*)d_out + 3200000);   // 3.2MB (dead before node_mfma)
    float*  agg3 = out_coord;

    char* ws = (char*)d_ws;
    __bf16* Pb       = (__bf16*)ws;                    //  6,400,000
    float* agg_edge  = (float*)(ws + 6400000);         // 12,800,000
    int*   deg       = (int*)(ws + 19200000);          //    200,000
    int*   base_rel  = (int*)(ws + 19400000);          //    200,000
    int2*  sorted_el = (int2*)(ws + 19600000);         //  6,400,000
    __bf16* W2T  = (__bf16*)(ws + 26000000);           // 8192 B each
    __bf16* Wc1T = W2T + 4096;
    __bf16* Wn2T = Wc1T + 4096;
    __bf16* Wn1T = Wn2T + 4096;                        // 16384 B -> ends 26,040,960
    int*   chunkSum = (int*)(ws + 26041088);           // 784 B

    hipMemsetAsync(deg, 0, (size_t)NN * sizeof(int), stream);

    prep_kernel<<<dim3(PREP_BLOCKS), dim3(256), 0, stream>>>(
        nf, el, We1, We2, Wc1, Wn1, Wn2, be1,
        W2T, Wc1T, Wn1T, Wn2T,
        Pa, Pb, deg, rank, agg_edge);

    alloc1_kernel<<<dim3(196), dim3(256), 0, stream>>>(deg, base_rel, chunkSum);

    scatter_kernel<<<dim3(NE / 256), dim3(256), 0, stream>>>(
        el, base_rel, chunkSum, rank, sorted_el, agg3);

    edge_mfma<<<dim3(NE / 128), dim3(128), 0, stream>>>(
        Pa, Pb, coord, sorted_el, We1, W2T, be2, Wc1T, bc1, wc,
        agg_edge, agg3);

    node_mfma<<<dim3((NN + 127) / 128), dim3(128), 0, stream>>>(
        nf, coord, agg_edge, deg, agg3, Wn1T, bn1, Wn2T, bn2, out_feat);
}

// Round 14
// 164.647 us; speedup vs baseline: 1.0290x; 1.0290x over previous
//
#include <hip/hip_runtime.h>
#include <hip/hip_fp8.h>

#define NN 50000
#define NE 800000
#define PREP_BLOCKS 784
#define PREP_THREADS (PREP_BLOCKS * 256)

typedef __bf16 bf16x8 __attribute__((ext_vector_type(8)));
typedef float  f32x4  __attribute__((ext_vector_type(4)));
typedef float  f32x2  __attribute__((ext_vector_type(2)));

#if defined(__has_builtin)
#if __has_builtin(__builtin_amdgcn_cvt_pk_f32_fp8)
#define HAVE_CVT_PK_FP8 1
#endif
#endif

__device__ __forceinline__ float frelu(float x) { return fmaxf(x, 0.f); }

__device__ __forceinline__ float fp8_to_f32(unsigned char b) {
    __hip_fp8_e4m3 t; t.__x = (__hip_fp8_storage_t)b; return (float)t;
}
__device__ __forceinline__ unsigned char f32_to_fp8(float f) {
    return (unsigned char)__hip_fp8_e4m3(f).__x;
}

// ===========================================================================
// prep: weight prep for later kernels + agg_edge zero + histogram with ranks
//       + Pa(fp8)/Pb(bf16) precompute (We1 via block-local LDS transpose).
__global__ __launch_bounds__(256) void prep_kernel(
    const float* __restrict__ nf, const int* __restrict__ el,
    const float* __restrict__ We1, const float* __restrict__ We2,
    const float* __restrict__ Wc1, const float* __restrict__ Wn1,
    const float* __restrict__ Wn2, const float* __restrict__ be1,
    __bf16* __restrict__ W2T,  __bf16* __restrict__ Wc1T,
    __bf16* __restrict__ Wn1T, __bf16* __restrict__ Wn2T,
    unsigned char* __restrict__ Pa, __bf16* __restrict__ Pb,
    int* __restrict__ deg, int* __restrict__ rank, float* __restrict__ agg_edge)
{
    __shared__ __align__(16) __bf16 w1lds[64 * 128];
    if (blockIdx.x < 196) {
        for (int idx = threadIdx.x; idx < 64 * 128; idx += 256) {
            const int k = idx >> 6;          // 0..127
            const int j = idx & 63;
            w1lds[j * 128 + (k ^ ((j & 7) << 3))] = (__bf16)We1[k * 64 + j];
        }
    }

    const int tid = blockIdx.x * 256 + threadIdx.x;

    // ---- weight transpose for later kernels (first 4096 threads) ----
    if (tid < 4096) {
        const int j = tid & 63, k = tid >> 6;
        W2T [j * 64 + k] = (__bf16)We2[k * 64 + j];
        Wc1T[j * 64 + k] = (__bf16)Wc1[k * 64 + j];
        Wn2T[j * 64 + k] = (__bf16)Wn2[k * 64 + j];
        Wn1T[j * 128 + k]      = (__bf16)Wn1[k * 64 + j];
        Wn1T[j * 128 + 64 + k] = (__bf16)Wn1[(64 + k) * 64 + j];
    }

    // ---- agg_edge zero (3.2M floats as float4) ----
    {
        const f32x4 z = (f32x4){0.f, 0.f, 0.f, 0.f};
        for (int i = tid; i < NN * 16; i += PREP_THREADS)
            ((f32x4*)agg_edge)[i] = z;
    }

    // ---- histogram + rank (deg memset to 0 before this kernel) ----
    for (int e = tid; e < NE; e += PREP_THREADS) {
        const int2 pr = ((const int2*)el)[e];
        rank[e] = atomicAdd(&deg[pr.y], 1);
    }

    if (blockIdx.x >= 196) return;
    __syncthreads();   // w1lds ready

    // ---- Pa/Pb MFMA precompute ----
    const int w = threadIdx.x >> 6, lane = threadIdx.x & 63;
    const int c = lane & 15, g = lane >> 4;
    const int mbase = blockIdx.x * 256 + w * 64;

    bf16x8 af[4][2];
#pragma unroll
    for (int m = 0; m < 4; ++m) {
        int node = mbase + m * 16 + c;
        node = (node < NN) ? node : (NN - 1);
#pragma unroll
        for (int s = 0; s < 2; ++s) {
            const int k0 = s * 32 + g * 8;
            const float4 v0 = *(const float4*)(nf + (size_t)node * 64 + k0);
            const float4 v1 = *(const float4*)(nf + (size_t)node * 64 + k0 + 4);
            bf16x8 a;
            a[0] = (__bf16)v0.x; a[1] = (__bf16)v0.y; a[2] = (__bf16)v0.z; a[3] = (__bf16)v0.w;
            a[4] = (__bf16)v1.x; a[5] = (__bf16)v1.y; a[6] = (__bf16)v1.z; a[7] = (__bf16)v1.w;
            af[m][s] = a;
        }
    }

    // Pa = nf @ We1[0:64,:]  -> fp8 e4m3
    {
        f32x4 cc[4][4];
#pragma unroll
        for (int m = 0; m < 4; ++m)
#pragma unroll
            for (int n = 0; n < 4; ++n) cc[m][n] = (f32x4){0.f, 0.f, 0.f, 0.f};
#pragma unroll
        for (int n = 0; n < 4; ++n)
#pragma unroll
            for (int s = 0; s < 2; ++s) {
                const int j = n * 16 + c;
                const bf16x8 b = *(const bf16x8*)&w1lds[j * 128 + ((s * 32 + g * 8) ^ ((j & 7) << 3))];
#pragma unroll
                for (int m = 0; m < 4; ++m)
                    cc[m][n] = __builtin_amdgcn_mfma_f32_16x16x32_bf16(af[m][s], b, cc[m][n], 0, 0, 0);
            }
#pragma unroll
        for (int m = 0; m < 4; ++m)
#pragma unroll
            for (int n = 0; n < 4; ++n)
#pragma unroll
                for (int r = 0; r < 4; ++r) {
                    const int node = mbase + m * 16 + g * 4 + r;
                    if (node < NN) Pa[(size_t)node * 64 + n * 16 + c] = f32_to_fp8(cc[m][n][r]);
                }
    }
    // Pb = nf @ We1[64:128,:] + be1 (folded)
    {
        f32x4 cc[4][4];
#pragma unroll
        for (int m = 0; m < 4; ++m)
#pragma unroll
            for (int n = 0; n < 4; ++n) cc[m][n] = (f32x4){0.f, 0.f, 0.f, 0.f};
#pragma unroll
        for (int n = 0; n < 4; ++n)
#pragma unroll
            for (int s = 0; s < 2; ++s) {
                const int j = n * 16 + c;
                const bf16x8 b = *(const bf16x8*)&w1lds[j * 128 + 64 + ((s * 32 + g * 8) ^ ((j & 7) << 3))];
#pragma unroll
                for (int m = 0; m < 4; ++m)
                    cc[m][n] = __builtin_amdgcn_mfma_f32_16x16x32_bf16(af[m][s], b, cc[m][n], 0, 0, 0);
            }
#pragma unroll
        for (int n = 0; n < 4; ++n) {
            const float bb = be1[n * 16 + c];
#pragma unroll
            for (int m = 0; m < 4; ++m)
#pragma unroll
                for (int r = 0; r < 4; ++r) {
                    const int node = mbase + m * 16 + g * 4 + r;
                    if (node < NN) Pb[(size_t)node * 64 + n * 16 + c] = (__bf16)(cc[m][n][r] + bb);
                }
        }
    }
}

// ===========================================================================
// alloc1: per-256-node chunk: exclusive prefix of deg within chunk + chunk sum.
__global__ __launch_bounds__(256) void alloc1_kernel(
    const int* __restrict__ deg, int* __restrict__ base_rel,
    int* __restrict__ chunkSum)
{
    __shared__ int wsum[4];
    const int t = threadIdx.x;
    const int n = blockIdx.x * 256 + t;
    const int lid = t & 63, wid = t >> 6;
    const int d = (n < NN) ? deg[n] : 0;
    int pre = d;
#pragma unroll
    for (int off = 1; off < 64; off <<= 1) {
        const int v = __shfl_up(pre, off);
        if (lid >= off) pre += v;
    }
    if (lid == 63) wsum[wid] = pre;
    __syncthreads();
    int woff = 0;
#pragma unroll
    for (int i = 0; i < 4; ++i) if (i < wid) woff += wsum[i];
    if (n < NN) base_rel[n] = woff + pre - d;
    if (t == 255) chunkSum[blockIdx.x] = woff + pre;
}

// ===========================================================================
// scatter: block-local scan of the 196 chunk sums (alloc2 fused) +
//          atomic-free placement + agg3 zeroing.
__global__ __launch_bounds__(256) void scatter_kernel(
    const int* __restrict__ el, const int* __restrict__ base_rel,
    const int* __restrict__ chunkSum, const int* __restrict__ rank,
    int2* __restrict__ sorted_el, float* __restrict__ agg3)
{
    __shared__ int s[256];
    __shared__ int cOff[196];
    const int t = threadIdx.x;
    const int v0 = (t < 196) ? chunkSum[t] : 0;
    s[t] = v0;
    __syncthreads();
    for (int d = 1; d < 256; d <<= 1) {
        const int v = (t >= d) ? s[t - d] : 0;
        __syncthreads();
        s[t] += v;
        __syncthreads();
    }
    if (t < 196) cOff[t] = s[t] - v0;
    __syncthreads();

    const int e = blockIdx.x * 256 + t;
    if (e < NN * 3) agg3[e] = 0.f;
    const int2 pr = ((const int2*)el)[e];
    sorted_el[cOff[pr.y >> 8] + base_rel[pr.y] + rank[e]] = pr;
}

// ===========================================================================
// Edge kernel (round-12 structure). 2 waves/block, 64 edges/wave.
// Agg scan: ALL 32 column values batch-read into registers (independent
// ds_reads, one latency exposure) + shfl-based nout boundaries (no LDS chain).
__global__ __launch_bounds__(128, 4) void edge_mfma(
    const unsigned char* __restrict__ Pa, const __bf16* __restrict__ Pb,
    const float* __restrict__ coord, const int2* __restrict__ sorted_el,
    const float* __restrict__ We1,
    const __bf16* __restrict__ W2T, const float* __restrict__ be2,
    const __bf16* __restrict__ Wc1T, const float* __restrict__ bc1,
    const float* __restrict__ wc,
    float* __restrict__ agg_edge, float* __restrict__ agg3)
{
    __shared__ __align__(16) __bf16 tile[2][64 * 32];  // half-width ef, swizzled
    __shared__ int   nout_s[2][64];
    __shared__ float tw_s[2][64];

    const int w    = threadIdx.x >> 6;                 // 0..1
    const int lane = threadIdx.x & 63;
    const int c    = lane & 15;
    const int g    = lane >> 4;
    const int ebase = blockIdx.x * 128 + w * 64;       // NE = 6250*128 exact

    // ---- phase 1: lane = edge (grouped+ascending by nout) ----
    const int2 pr = sorted_el[ebase + lane];
    const int nin = pr.x, nout = pr.y;
    nout_s[w][lane] = nout;
    const float cdx = coord[3 * nout + 0] - coord[3 * nin + 0];
    const float cdy = coord[3 * nout + 1] - coord[3 * nin + 1];
    const float cdz = coord[3 * nout + 2] - coord[3 * nin + 2];
    const float radial = cdx * cdx + cdy * cdy + cdz * cdz;

    // We1 radial row (be1 folded into Pb at prep)
    float wv[2][8];
#pragma unroll
    for (int s = 0; s < 2; ++s) {
        const int k0 = s * 32 + g * 8;
        const float4 a = *(const float4*)(We1 + 128 * 64 + k0);
        const float4 b = *(const float4*)(We1 + 128 * 64 + k0 + 4);
        wv[s][0] = a.x; wv[s][1] = a.y; wv[s][2] = a.z; wv[s][3] = a.w;
        wv[s][4] = b.x; wv[s][5] = b.y; wv[s][6] = b.z; wv[s][7] = b.w;
    }

    // ---- build A fragments of h directly in MFMA A-layout (shfl broadcast) ----
    bf16x8 af[4][2];
#pragma unroll
    for (int m = 0; m < 4; ++m) {
        const int e   = m * 16 + c;
        const int ni  = __shfl(nin, e);
        const int no  = __shfl(nout, e);
        const float rad = __shfl(radial, e);
        const unsigned char* paRow = Pa + (size_t)ni * 64;
        const __bf16* pbRow = Pb + (size_t)no * 64;
#pragma unroll
        for (int s = 0; s < 2; ++s) {
            const int k0 = s * 32 + g * 8;
            const uint2 pu = *(const uint2*)(paRow + k0);   // 8 fp8 bytes
            const bf16x8 pb = *(const bf16x8*)(pbRow + k0);
            float pav[8];
#if defined(HAVE_CVT_PK_FP8)
            {
                const f32x2 v01 = __builtin_amdgcn_cvt_pk_f32_fp8((int)pu.x, false);
                const f32x2 v23 = __builtin_amdgcn_cvt_pk_f32_fp8((int)pu.x, true);
                const f32x2 v45 = __builtin_amdgcn_cvt_pk_f32_fp8((int)pu.y, false);
                const f32x2 v67 = __builtin_amdgcn_cvt_pk_f32_fp8((int)pu.y, true);
                pav[0] = v01[0]; pav[1] = v01[1]; pav[2] = v23[0]; pav[3] = v23[1];
                pav[4] = v45[0]; pav[5] = v45[1]; pav[6] = v67[0]; pav[7] = v67[1];
            }
#else
#pragma unroll
            for (int i = 0; i < 8; ++i) {
                const unsigned char pbyte =
                    (unsigned char)(((i < 4 ? pu.x : pu.y) >> (8 * (i & 3))) & 0xFF);
                pav[i] = fp8_to_f32(pbyte);
            }
#endif
            bf16x8 a;
#pragma unroll
            for (int i = 0; i < 8; ++i)
                a[i] = (__bf16)frelu(pav[i] + (float)pb[i] + rad * wv[s][i]);
            af[m][s] = a;
        }
    }

    // ---- GEMM1 + ef staging + agg, in two 32-column phases ----
    bf16x8 a2[4][2];
#pragma unroll
    for (int p = 0; p < 2; ++p) {
        f32x4 c1h[4][2];
#pragma unroll
        for (int q = 0; q < 2; ++q) {
            const float b = be2[(2 * p + q) * 16 + c];
#pragma unroll
            for (int m = 0; m < 4; ++m) c1h[m][q] = (f32x4){b, b, b, b};
        }
#pragma unroll
        for (int q = 0; q < 2; ++q)
#pragma unroll
            for (int s = 0; s < 2; ++s) {
                const bf16x8 b = *(const bf16x8*)(W2T + ((2 * p + q) * 16 + c) * 64 + s * 32 + g * 8);
#pragma unroll
                for (int m = 0; m < 4; ++m)
                    c1h[m][q] = __builtin_amdgcn_mfma_f32_16x16x32_bf16(af[m][s], b, c1h[m][q], 0, 0, 0);
            }

#pragma unroll
        for (int m = 0; m < 4; ++m)
#pragma unroll
            for (int q = 0; q < 2; ++q)
#pragma unroll
                for (int r = 0; r < 4; ++r) {
                    const int e = m * 16 + g * 4 + r;
                    const int lc = q * 16 + c;
                    tile[w][e * 32 + (lc ^ (((e >> 1) & 3) << 3))] = (__bf16)frelu(c1h[m][q][r]);
                }

#pragma unroll
        for (int m = 0; m < 4; ++m) {
            const int e = m * 16 + c;
            a2[m][p] = *(const bf16x8*)&tile[w][e * 32 + ((g * 8) ^ (((e >> 1) & 3) << 3))];
        }

        // agg_edge for cols p*32..p*32+31: 2 lanes/col, rows split 0-31/32-63.
        // Batch all 32 ds_reads into registers (independent), then pure-VALU
        // scan with shfl-based run boundaries -- no serial LDS chain.
        {
            const int lc = lane & 31;
            const int rbase = (lane >> 5) * 32;
            float v[32];
#pragma unroll
            for (int rr = 0; rr < 32; ++rr) {
                const int r = rbase + rr;
                v[rr] = (float)tile[w][r * 32 + (lc ^ (((r >> 1) & 3) << 3))];
            }
            int cur = __shfl(nout, rbase);
            float acc = 0.f;
#pragma unroll
            for (int rr = 0; rr < 32; ++rr) {
                acc += v[rr];
                const int nxt = (rr < 31) ? __shfl(nout, rbase + rr + 1) : -1;
                if (nxt != cur) {
                    atomicAdd(&agg_edge[(size_t)cur * 64 + p * 32 + lc], acc);
                    acc = 0.f;
                    cur = nxt;
                }
            }
        }
    }

    // ---- GEMM2 (t = relu(ef @ Wc1 + bc1)) folded into tw per n ----
    f32x4 twp[4];
#pragma unroll
    for (int m = 0; m < 4; ++m) twp[m] = (f32x4){0.f, 0.f, 0.f, 0.f};
#pragma unroll
    for (int n = 0; n < 4; ++n) {
        const float b = bc1[n * 16 + c];
        const float wn = wc[n * 16 + c];
        f32x4 c2[4];
#pragma unroll
        for (int m = 0; m < 4; ++m) c2[m] = (f32x4){b, b, b, b};
#pragma unroll
        for (int s = 0; s < 2; ++s) {
            const bf16x8 bb = *(const bf16x8*)(Wc1T + (n * 16 + c) * 64 + s * 32 + g * 8);
#pragma unroll
            for (int m = 0; m < 4; ++m)
                c2[m] = __builtin_amdgcn_mfma_f32_16x16x32_bf16(a2[m][s], bb, c2[m], 0, 0, 0);
        }
#pragma unroll
        for (int m = 0; m < 4; ++m)
#pragma unroll
            for (int r = 0; r < 4; ++r)
                twp[m][r] = fmaf(frelu(c2[m][r]), wn, twp[m][r]);
    }

    // ---- tw: 16-lane butterfly reduce ----
#pragma unroll
    for (int m = 0; m < 4; ++m) {
#pragma unroll
        for (int r = 0; r < 4; ++r) {
            float p = twp[m][r];
            p += __shfl_xor(p, 1);
            p += __shfl_xor(p, 2);
            p += __shfl_xor(p, 4);
            p += __shfl_xor(p, 8);
            if (c == 0) tw_s[w][m * 16 + g * 4 + r] = p;
        }
    }

    // ---- coord agg: 48 lanes = 16 row-chunks x 3 dims, run-compressed ----
    {
        const bool act = (lane < 48);
        const int dim = lane % 3;
        const int chunk = act ? (lane / 3) : 0;       // 0..15
        const int r0 = chunk * 4;
        // hoist the 4 tw_s reads (independent) before the scan
        float twv[4];
#pragma unroll
        for (int rr = 0; rr < 4; ++rr) twv[rr] = tw_s[w][r0 + rr];
        int cur = nout_s[w][r0];
        float acc = 0.f;
#pragma unroll
        for (int rr = 0; rr < 4; ++rr) {
            const int r = r0 + rr;
            const float sx = __shfl(cdx, r);
            const float sy = __shfl(cdy, r);
            const float sz = __shfl(cdz, r);
            const float cdv = (dim == 0) ? sx : (dim == 1) ? sy : sz;
            acc += cdv * twv[rr];
            const int nxt = (rr < 3) ? nout_s[w][r + 1] : -1;
            if (nxt != cur) {
                if (act) atomicAdd(&agg3[3 * cur + dim], acc);
                acc = 0.f;
                cur = nxt;
            }
        }
    }
}

// ===========================================================================
// Node kernel: coord finalize + node MLP via MFMA. 2 waves/block (barrier-free).
__global__ __launch_bounds__(128) void node_mfma(
    const float* __restrict__ nf, const float* __restrict__ coord,
    const float* __restrict__ agg_edge, const int* __restrict__ deg,
    float* agg3_coordout,
    const __bf16* __restrict__ Wn1T, const float* __restrict__ bn1,
    const __bf16* __restrict__ Wn2T, const float* __restrict__ bn2,
    float* __restrict__ out_feat)
{
    __shared__ __align__(16) __bf16 tile[2][64 * 64];
    const int t = threadIdx.x;
    const int w = t >> 6, lane = t & 63, c = lane & 15, g = lane >> 4;
    const int nblk = blockIdx.x * 128;

    const int nodeT = nblk + t;
    if (nodeT < NN) {
        const float invc = 1.f / fmaxf((float)deg[nodeT], 1.f);
#pragma unroll
        for (int d = 0; d < 3; ++d) {
            const float a = agg3_coordout[3 * nodeT + d];
            agg3_coordout[3 * nodeT + d] = coord[3 * nodeT + d] + a * invc;
        }
    }

    const int mbase = nblk + w * 64;

    bf16x8 a1[4][4];
#pragma unroll
    for (int m = 0; m < 4; ++m) {
        int node = mbase + m * 16 + c;
        node = (node < NN) ? node : (NN - 1);
#pragma unroll
        for (int s = 0; s < 4; ++s) {
            const int k0 = s * 32 + g * 8;
            const float* src = (k0 < 64) ? (nf + (size_t)node * 64 + k0)
                                         : (agg_edge + (size_t)node * 64 + (k0 - 64));
            const float4 v0 = *(const float4*)src;
            const float4 v1 = *(const float4*)(src + 4);
            bf16x8 a;
            a[0] = (__bf16)v0.x; a[1] = (__bf16)v0.y; a[2] = (__bf16)v0.z; a[3] = (__bf16)v0.w;
            a[4] = (__bf16)v1.x; a[5] = (__bf16)v1.y; a[6] = (__bf16)v1.z; a[7] = (__bf16)v1.w;
            a1[m][s] = a;
        }
    }

    f32x4 c1[4][4];
#pragma unroll
    for (int n = 0; n < 4; ++n) {
        const float b = bn1[n * 16 + c];
#pragma unroll
        for (int m = 0; m < 4; ++m) c1[m][n] = (f32x4){b, b, b, b};
    }
#pragma unroll
    for (int n = 0; n < 4; ++n)
#pragma unroll
        for (int s = 0; s < 4; ++s) {
            const bf16x8 b = *(const bf16x8*)(Wn1T + (n * 16 + c) * 128 + s * 32 + g * 8);
#pragma unroll
            for (int m = 0; m < 4; ++m)
                c1[m][n] = __builtin_amdgcn_mfma_f32_16x16x32_bf16(a1[m][s], b, c1[m][n], 0, 0, 0);
        }

#pragma unroll
    for (int m = 0; m < 4; ++m)
#pragma unroll
        for (int n = 0; n < 4; ++n)
#pragma unroll
            for (int r = 0; r < 4; ++r) {
                const int e = m * 16 + g * 4 + r;
                tile[w][e * 64 + ((n * 16 + c) ^ ((e & 7) << 3))] = (__bf16)frelu(c1[m][n][r]);
            }

    bf16x8 a2[4][2];
#pragma unroll
    for (int m = 0; m < 4; ++m) {
        const int e = m * 16 + c;
#pragma unroll
        for (int s = 0; s < 2; ++s) {
            const int k0 = s * 32 + g * 8;
            a2[m][s] = *(const bf16x8*)&tile[w][e * 64 + (k0 ^ ((e & 7) << 3))];
        }
    }
    f32x4 c2[4][4];
#pragma unroll
    for (int n = 0; n < 4; ++n) {
        const float b = bn2[n * 16 + c];
#pragma unroll
        for (int m = 0; m < 4; ++m) c2[m][n] = (f32x4){b, b, b, b};
    }
#pragma unroll
    for (int n = 0; n < 4; ++n)
#pragma unroll
        for (int s = 0; s < 2; ++s) {
            const bf16x8 b = *(const bf16x8*)(Wn2T + (n * 16 + c) * 64 + s * 32 + g * 8);
#pragma unroll
            for (int m = 0; m < 4; ++m)
                c2[m][n] = __builtin_amdgcn_mfma_f32_16x16x32_bf16(a2[m][s], b, c2[m][n], 0, 0, 0);
        }

#pragma unroll
    for (int m = 0; m < 4; ++m)
#pragma unroll
        for (int n = 0; n < 4; ++n)
#pragma unroll
            for (int r = 0; r < 4; ++r) {
                const int node = mbase + m * 16 + g * 4 + r;
                if (node < NN) {
                    const int col = n * 16 + c;
                    out_feat[(size_t)node * 64 + col] =
                        nf[(size_t)node * 64 + col] + c2[m][n][r];
                }
            }
}

// ===========================================================================
extern "C" void kernel_launch(void* const* d_in, const int* in_sizes, int n_in,
                              void* d_out, int out_size, void* d_ws, size_t ws_size,
                              hipStream_t stream)
{
    const float* nf    = (const float*)d_in[0];
    const float* coord = (const float*)d_in[1];
    const int*   el    = (const int*)d_in[2];
    const float* We1   = (const float*)d_in[3];
    const float* be1   = (const float*)d_in[4];
    const float* We2   = (const float*)d_in[5];
    const float* be2   = (const float*)d_in[6];
    const float* Wn1   = (const float*)d_in[7];
    const float* bn1   = (const float*)d_in[8];
    const float* Wn2   = (const float*)d_in[9];
    const float* bn2   = (const float*)d_in[10];
    const float* Wc1   = (const float*)d_in[11];
    const float* bc1   = (const float*)d_in[12];
    const float* wc    = (const float*)d_in[13];

    float* out_feat  = (float*)d_out;               // N*64 f32
    float* out_coord = out_feat + (size_t)NN * 64;  // N*3 f32

    unsigned char* Pa = (unsigned char*)d_out;       // 3.2MB of out_feat region
    int*    rank = (int*)((char*)d_out + 3200000);   // 3.2MB (dead before node_mfma)
    float*  agg3 = out_coord;

    char* ws = (char*)d_ws;
    __bf16* Pb       = (__bf16*)ws;                    //  6,400,000
    float* agg_edge  = (float*)(ws + 6400000);         // 12,800,000
    int*   deg       = (int*)(ws + 19200000);          //    200,000
    int*   base_rel  = (int*)(ws + 19400000);          //    200,000
    int2*  sorted_el = (int2*)(ws + 19600000);         //  6,400,000
    __bf16* W2T  = (__bf16*)(ws + 26000000);           // 8192 B each
    __bf16* Wc1T = W2T + 4096;
    __bf16* Wn2T = Wc1T + 4096;
    __bf16* Wn1T = Wn2T + 4096;                        // 16384 B -> ends 26,040,960
    int*   chunkSum = (int*)(ws + 26041088);           // 784 B

    hipMemsetAsync(deg, 0, (size_t)NN * sizeof(int), stream);

    prep_kernel<<<dim3(PREP_BLOCKS), dim3(256), 0, stream>>>(
        nf, el, We1, We2, Wc1, Wn1, Wn2, be1,
        W2T, Wc1T, Wn1T, Wn2T,
        Pa, Pb, deg, rank, agg_edge);

    alloc1_kernel<<<dim3(196), dim3(256), 0, stream>>>(deg, base_rel, chunkSum);

    scatter_kernel<<<dim3(NE / 256), dim3(256), 0, stream>>>(
        el, base_rel, chunkSum, rank, sorted_el, agg3);

    edge_mfma<<<dim3(NE / 128), dim3(128), 0, stream>>>(
        Pa, Pb, coord, sorted_el, We1, W2T, be2, Wc1T, bc1, wc,
        agg_edge, agg3);

    node_mfma<<<dim3((NN + 127) / 128), dim3(128), 0, stream>>>(
        nf, coord, agg_edge, deg, agg3, Wn1T, bn1, Wn2T, bn2, out_feat);
}